// Round 1
// baseline (180.303 us; speedup 1.0000x reference)
//
#include <hip/hip_runtime.h>

#define B_DIM 4096
#define L_DIM 2048
#define TPB   256
#define EPT   8                      // L_DIM / TPB
#define TAU_INV 1.0526315789473684f  // 1/0.95

// One block per row. Computes:
//   partials[row]         = sum_j log(t_j/tau) * q_j   (softmax-weighted)
//   partials[B_DIM + row] = sum_j sum_{views} (y*logp + (1-y)*log1mp)
__global__ __launch_bounds__(TPB) void milecut_row_kernel(
    const float* __restrict__ trunc,
    const float* __restrict__ view1,
    const float* __restrict__ view2,
    const float* __restrict__ view3,
    const float* __restrict__ labels,
    float* __restrict__ partials)
{
    const int row = blockIdx.x;
    const int t   = threadIdx.x;
    const size_t rowOff = (size_t)row * L_DIM;

    __shared__ float sdata[TPB];

    // ---- load labels: 8 contiguous elems per thread via 2x float4 ----
    const float4* y4 = (const float4*)(labels + rowOff) + t * 2;
    float4 ya = y4[0];
    float4 yb = y4[1];
    float y[EPT] = {ya.x, ya.y, ya.z, ya.w, yb.x, yb.y, yb.z, yb.w};

    float lsum = 0.f;
    #pragma unroll
    for (int k = 0; k < EPT; ++k) lsum += y[k];

    // ---- inclusive scan of per-thread sums (Hillis-Steele in LDS) ----
    // labels are exactly 0/1 -> sums are exact small integers in fp32
    sdata[t] = lsum;
    __syncthreads();
    for (int off = 1; off < TPB; off <<= 1) {
        float v   = sdata[t];
        float add = (t >= off) ? sdata[t - off] : 0.f;
        __syncthreads();
        sdata[t] = v + add;
        __syncthreads();
    }
    float total = sdata[TPB - 1];          // row total labels
    float run   = (t > 0) ? sdata[t - 1] : 0.f;  // exclusive prefix
    __syncthreads();

    // ---- r = where(cum>0, 2*cum/(k+total), 0); x = r/tau; track max ----
    float x[EPT];
    float m = 0.f;   // r >= 0 always
    #pragma unroll
    for (int k = 0; k < EPT; ++k) {
        run += y[k];                               // inclusive cumsum
        float denom = (float)(t * EPT + k + 1) + total;
        float r = (run > 0.f) ? (2.f * run) / denom : 0.f;
        x[k] = r * TAU_INV;
        m = fmaxf(m, x[k]);
    }

    // ---- block max ----
    sdata[t] = m;
    __syncthreads();
    for (int off = TPB / 2; off > 0; off >>= 1) {
        if (t < off) sdata[t] = fmaxf(sdata[t], sdata[t + off]);
        __syncthreads();
    }
    m = sdata[0];
    __syncthreads();

    // ---- exp(x - m), block sum ----
    float esum = 0.f;
    #pragma unroll
    for (int k = 0; k < EPT; ++k) { x[k] = __expf(x[k] - m); esum += x[k]; }

    sdata[t] = esum;
    __syncthreads();
    for (int off = TPB / 2; off > 0; off >>= 1) {
        if (t < off) sdata[t] += sdata[t + off];
        __syncthreads();
    }
    float s = sdata[0];
    __syncthreads();

    // ---- trunc: sum log(t/tau) * e  (divide by s at the end) ----
    const float4* t4 = (const float4*)(trunc + rowOff) + t * 2;
    float4 ta = t4[0];
    float4 tb = t4[1];
    float tv[EPT] = {ta.x, ta.y, ta.z, ta.w, tb.x, tb.y, tb.z, tb.w};
    float wtr = 0.f;
    #pragma unroll
    for (int k = 0; k < EPT; ++k) wtr += __logf(tv[k] * TAU_INV) * x[k];

    // ---- BCE for 3 views. y in {0,1} exactly:
    //      y*logp + (1-y)*log1mp == log(y ? p : 1-p), clamped at -100 ----
    float bce = 0.f;
    const float* views[3] = {view1, view2, view3};
    #pragma unroll
    for (int vi = 0; vi < 3; ++vi) {
        const float4* p4 = (const float4*)(views[vi] + rowOff) + t * 2;
        float4 pa = p4[0];
        float4 pb = p4[1];
        float pv[EPT] = {pa.x, pa.y, pa.z, pa.w, pb.x, pb.y, pb.z, pb.w};
        #pragma unroll
        for (int k = 0; k < EPT; ++k) {
            float sel = (y[k] > 0.5f) ? pv[k] : (1.0f - pv[k]);
            bce += fmaxf(__logf(sel), -100.0f);
        }
    }

    // ---- block reduce wtr, then bce ----
    sdata[t] = wtr;
    __syncthreads();
    for (int off = TPB / 2; off > 0; off >>= 1) {
        if (t < off) sdata[t] += sdata[t + off];
        __syncthreads();
    }
    float wsum = sdata[0];
    __syncthreads();

    sdata[t] = bce;
    __syncthreads();
    for (int off = TPB / 2; off > 0; off >>= 1) {
        if (t < off) sdata[t] += sdata[t + off];
        __syncthreads();
    }

    if (t == 0) {
        partials[row]         = wsum / s;   // sum_j log(t/tau)*q_j for this row
        partials[B_DIM + row] = sdata[0];   // combined bce raw sum for this row
    }
}

__global__ __launch_bounds__(TPB) void milecut_final_kernel(
    const float* __restrict__ partials, float* __restrict__ out)
{
    const int t = threadIdx.x;
    float st = 0.f, sb = 0.f;
    for (int i = t; i < B_DIM; i += TPB) {
        st += partials[i];
        sb += partials[B_DIM + i];
    }
    __shared__ float s1[TPB];
    __shared__ float s2[TPB];
    s1[t] = st; s2[t] = sb;
    __syncthreads();
    for (int off = TPB / 2; off > 0; off >>= 1) {
        if (t < off) { s1[t] += s1[t + off]; s2[t] += s2[t + off]; }
        __syncthreads();
    }
    if (t == 0) {
        double St = (double)s1[0];
        double Sb = (double)s2[0];
        // trunc_loss = -sum(log_out * q) / B
        double trunc_loss = -St / (double)B_DIM;
        // v1+v2+v3 = -(S1+S2+S3) / (B*L) / B
        double vsum = -Sb / ((double)B_DIM * (double)L_DIM * (double)B_DIM);
        out[0] = (float)(0.5 * trunc_loss + 0.5 * vsum);
    }
}

extern "C" void kernel_launch(void* const* d_in, const int* in_sizes, int n_in,
                              void* d_out, int out_size, void* d_ws, size_t ws_size,
                              hipStream_t stream) {
    const float* trunc  = (const float*)d_in[0];
    const float* v1     = (const float*)d_in[1];
    const float* v2     = (const float*)d_in[2];
    const float* v3     = (const float*)d_in[3];
    const float* labels = (const float*)d_in[4];

    float* partials = (float*)d_ws;  // needs 2*B_DIM*4 = 32 KB

    milecut_row_kernel<<<B_DIM, TPB, 0, stream>>>(trunc, v1, v2, v3, labels, partials);
    milecut_final_kernel<<<1, TPB, 0, stream>>>(partials, (float*)d_out);
}